// Round 1
// baseline (586.708 us; speedup 1.0000x reference)
//
#include <hip/hip_runtime.h>
#include <cstdint>

// Fully coalesced scheme: lane i loads float4 #i (16B, consecutive across lanes).
// One element's 32 spike floats span 8 consecutive lanes (4 floats/lane).
// Each lane packs its 4 bits, pre-shifted into IEEE MSB-first position; a
// 3-step OR-butterfly across the aligned 8-lane group gives every lane the
// full 32-bit word. All 8 lanes redundantly do the IEEE fp32 multiply, then
// each lane unpacks its own 4 output bits -> coalesced float4 store.
//
// Round 1 changes vs baseline:
//  - Cross-lane OR-butterfly moved from __shfl_xor (LDS pipe: ds_swizzle,
//    ~120cy each, lgkmcnt stalls) to DPP on the VALU pipe (~2cy each):
//      xor1 = quad_perm:[1,0,3,2] (0xB1)
//      xor2 = quad_perm:[2,3,0,1] (0x4E)
//      xor4-equivalent = row_half_mirror (0x141)  [valid because after
//        xor1+xor2 all lanes of each 4-group hold the same value]
//  - Grid-stride loop (2048 blocks), 32 float4-groups/thread, unroll 4:
//    up to 8 independent global loads in flight per wave instead of 2.

#define OR_DPP(v, ctrl) \
    ((v) | (uint32_t)__builtin_amdgcn_update_dpp(0, (int)(v), (ctrl), 0xF, 0xF, true))

#define DPP_QUAD_XOR1 0xB1       // quad_perm:[1,0,3,2]
#define DPP_QUAD_XOR2 0x4E       // quad_perm:[2,3,0,1]
#define DPP_ROW_HALF_MIRROR 0x141  // lane i -> 7-i within each 8-lane group

__global__ __launch_bounds__(256) void spikefp32mul_kernel(
    const float4* __restrict__ A4, const float4* __restrict__ B4,
    float4* __restrict__ O4, int n4)
{
    const int stride = gridDim.x * blockDim.x;  // multiple of 256 -> multiple of 8
    int g0 = blockIdx.x * blockDim.x + threadIdx.x;

    // float index f = 4g + c belongs to element g/8, bit j = f%32 = 4*(g&7)+c,
    // which is IEEE bit 31-j. Nibble base shift; loop-invariant since stride%8==0.
    const int sb = 28 - 4 * (g0 & 7);

    #pragma unroll 4
    for (int g = g0; g < n4; g += stride) {
        float4 a = A4[g];
        float4 b = B4[g];

        uint32_t wa = ((a.x > 0.5f ? 8u : 0u) | (a.y > 0.5f ? 4u : 0u) |
                       (a.z > 0.5f ? 2u : 0u) | (a.w > 0.5f ? 1u : 0u)) << sb;
        uint32_t wb = ((b.x > 0.5f ? 8u : 0u) | (b.y > 0.5f ? 4u : 0u) |
                       (b.z > 0.5f ? 2u : 0u) | (b.w > 0.5f ? 1u : 0u)) << sb;

        // OR-butterfly across the 8 lanes of this element group (VALU DPP only).
        wa = OR_DPP(wa, DPP_QUAD_XOR1);
        wb = OR_DPP(wb, DPP_QUAD_XOR1);
        wa = OR_DPP(wa, DPP_QUAD_XOR2);
        wb = OR_DPP(wb, DPP_QUAD_XOR2);
        wa = OR_DPP(wa, DPP_ROW_HALF_MIRROR);
        wb = OR_DPP(wb, DPP_ROW_HALF_MIRROR);

        float p = __uint_as_float(wa) * __uint_as_float(wb);  // IEEE fp32 mul, RNE
        uint32_t wp = __float_as_uint(p);

        float4 o;
        o.x = (float)((wp >> (sb + 3)) & 1u);
        o.y = (float)((wp >> (sb + 2)) & 1u);
        o.z = (float)((wp >> (sb + 1)) & 1u);
        o.w = (float)((wp >> sb) & 1u);
        O4[g] = o;
    }
}

extern "C" void kernel_launch(void* const* d_in, const int* in_sizes, int n_in,
                              void* d_out, int out_size, void* d_ws, size_t ws_size,
                              hipStream_t stream) {
    const float4* A4 = (const float4*)d_in[0];
    const float4* B4 = (const float4*)d_in[1];
    float4* O4 = (float4*)d_out;

    int n4 = in_sizes[0] / 4;   // 16,777,216 float4s
    const int block = 256;
    int grid = 2048;            // 8 blocks/CU x 256 CU; grid-stride covers the rest
    int need = (n4 + block - 1) / block;
    if (grid > need) grid = need;
    spikefp32mul_kernel<<<grid, block, 0, stream>>>(A4, B4, O4, n4);
}